// Round 9
// baseline (299.852 us; speedup 1.0000x reference)
//
#include <hip/hip_runtime.h>
#include <math.h>

typedef _Float16 f16;
typedef _Float16 half8 __attribute__((ext_vector_type(8)));
typedef _Float16 half4 __attribute__((ext_vector_type(4)));
typedef float floatx4 __attribute__((ext_vector_type(4)));

constexpr int B   = 128;
constexpr int S   = 64;
constexpr int D0  = 768;
constexpr int H   = 256;
constexpr int KW  = 7;
constexpr int NC  = 3;
constexpr int T70 = S + KW - 1;  // 70
constexpr float EPSF = 1e-12f;
constexpr int KTOT1 = ((D0 / 64) * 7 + 7) * 64;   // 5824
constexpr int KTOT2 = ((H  / 64) * 7 + 7) * 64;   // 2240

// global_load_lds width=16: linear LDS dest (wave-uniform base + lane*16), per-lane global src
__device__ __forceinline__ void gload16(const void* g, void* l) {
  __builtin_amdgcn_global_load_lds(
      (const __attribute__((address_space(1))) unsigned int*)g,
      (__attribute__((address_space(3))) unsigned int*)l, 16, 0, 0);
}

// ---------- fused fp32->fp16 convert + mean over t, both sides ----------
__global__ __launch_bounds__(256) void k_cvtmean(const float* __restrict__ in0,
                                                 const float* __restrict__ in1,
                                                 f16* __restrict__ oh0,
                                                 f16* __restrict__ oh1,
                                                 float* __restrict__ mn0,
                                                 float* __restrict__ mn1) {
  constexpr int D4 = D0 / 4;
  const int side = blockIdx.y;
  const float* __restrict__ in = side ? in1 : in0;
  f16* __restrict__ outh = side ? oh1 : oh0;
  float* __restrict__ mean = side ? mn1 : mn0;
  const int idx = blockIdx.x * 256 + threadIdx.x;   // grid.x = B*D4/256 = 96
  const int b = idx / D4, f4 = idx % D4;
  const float4* __restrict__ src = reinterpret_cast<const float4*>(in) + (size_t)b * S * D4 + f4;
  half4* __restrict__ dst = reinterpret_cast<half4*>(outh) + (size_t)b * S * D4 + f4;
  float4 acc = {0.f, 0.f, 0.f, 0.f};
  for (int t = 0; t < S; ++t) {
    float4 v = src[(size_t)t * D4];
    acc.x += v.x; acc.y += v.y; acc.z += v.z; acc.w += v.w;
    half4 o = {(f16)v.x, (f16)v.y, (f16)v.z, (f16)v.w};
    dst[(size_t)t * D4] = o;
  }
  const float inv = 1.f / S;
  mean[(size_t)b * D0 + f4 * 4 + 0] = acc.x * inv;
  mean[(size_t)b * D0 + f4 * 4 + 1] = acc.y * inv;
  mean[(size_t)b * D0 + f4 * 4 + 2] = acc.z * inv;
  mean[(size_t)b * D0 + f4 * 4 + 3] = acc.w * inv;
}

// ---------- fused weight prep: X-part transpose + V-GEMM, both layers, one launch ----------
// Weff layout (pre-swizzled): X cols (dq*7+k)*64, att cols (NX7+k)*64;
// within each 64-col group, 16B chunk e>>3 stored at (e>>3)^(h&7).
__device__ __forceinline__ void trw_x_dev(const float* __restrict__ cw,
                                          f16* __restrict__ Weff,
                                          int DPC, int Ktot, int t,
                                          f16 (*tile)[65]) {
  const int nb = DPC / 64;
  const int k = t / (nb * 4);
  const int rem = t % (nb * 4);
  const int h0 = (rem / nb) * 64, dd0 = (rem % nb) * 64;
  const int tx = threadIdx.x & 63, ty = threadIdx.x >> 6;
#pragma unroll
  for (int i = 0; i < 64; i += 4) {
    int dd = dd0 + i + ty;
    tile[i + ty][tx] = (f16)cw[(size_t)((dd * KW + k) * 2 + 0) * H + h0 + tx];
  }
  __syncthreads();
  const int sbase = ((dd0 >> 6) * 7 + k) * 64;
#pragma unroll
  for (int i = 0; i < 64; i += 4) {
    int h = h0 + i + ty;
    int col = sbase + (((tx >> 3) ^ (h & 7)) << 3) + (tx & 7);
    Weff[(size_t)h * Ktot + col] = tile[tx][i + ty];
  }
}

__device__ __forceinline__ void vgemm_dev(const float* __restrict__ aW,
                                          const float* __restrict__ cw,
                                          f16* __restrict__ Weff,
                                          int D, int Ktot, int t,
                                          half8* As, half8* Bs) {
  const int kk = t % 7;
  const int h0 = (t / 7) * 64;
  const int tid = threadIdx.x;
  const int lane = tid & 63, wave = tid >> 6;
  const int wr = wave >> 1, wc = wave & 1;
  const int l15 = lane & 15, g = lane >> 4;

  floatx4 acc[2][2];
#pragma unroll
  for (int i = 0; i < 2; ++i)
#pragma unroll
    for (int j = 0; j < 2; ++j) acc[i][j] = (floatx4)0.f;

  for (int k0 = 0; k0 < D; k0 += 32) {
    __syncthreads();
    {
      const int r = tid >> 2, cch = tid & 3;
      const float4* s = reinterpret_cast<const float4*>(aW + (size_t)r * D + k0 + cch * 8);
      float4 v0 = s[0], v1 = s[1];
      half8 hv = {(f16)v0.x, (f16)v0.y, (f16)v0.z, (f16)v0.w,
                  (f16)v1.x, (f16)v1.y, (f16)v1.z, (f16)v1.w};
      As[r * 4 + (cch ^ ((r >> 1) & 3))] = hv;
      const int hrow = tid & 63, kc = tid >> 6;
      half8 bv;
#pragma unroll
      for (int e = 0; e < 8; ++e) {
        const int d = k0 + kc * 8 + e;
        bv[e] = (f16)cw[(size_t)((d * KW + kk) * 2 + 1) * H + h0 + hrow];
      }
      Bs[hrow * 4 + (kc ^ ((hrow >> 1) & 3))] = bv;
    }
    __syncthreads();
    half8 af[2], bf[2];
#pragma unroll
    for (int fi = 0; fi < 2; ++fi) {
      const int row = wr * 32 + fi * 16 + l15;
      af[fi] = As[row * 4 + (g ^ ((row >> 1) & 3))];
    }
#pragma unroll
    for (int fj = 0; fj < 2; ++fj) {
      const int row = wc * 32 + fj * 16 + l15;
      bf[fj] = Bs[row * 4 + (g ^ ((row >> 1) & 3))];
    }
#pragma unroll
    for (int fi = 0; fi < 2; ++fi)
#pragma unroll
      for (int fj = 0; fj < 2; ++fj)
        acc[fi][fj] = __builtin_amdgcn_mfma_f32_16x16x32_f16(af[fi], bf[fj], acc[fi][fj], 0, 0, 0);
  }
  const int base = ((D / 64) * 7 + kk) * 64;
#pragma unroll
  for (int fi = 0; fi < 2; ++fi)
#pragma unroll
    for (int fj = 0; fj < 2; ++fj)
#pragma unroll
      for (int r = 0; r < 4; ++r) {
        const int j = wr * 32 + fi * 16 + g * 4 + r;
        const int h = h0 + wc * 32 + fj * 16 + l15;
        const int col = base + (((j >> 3) ^ (h & 7)) << 3) + (j & 7);
        Weff[(size_t)h * Ktot + col] = (f16)acc[fi][fj][r];
      }
}

__global__ __launch_bounds__(256) void k_wprep(const float* __restrict__ cw1,
                                               const float* __restrict__ aW1,
                                               f16* __restrict__ Weff1,
                                               const float* __restrict__ cw2,
                                               const float* __restrict__ aW2,
                                               f16* __restrict__ Weff2) {
  __shared__ f16 tile[64][65];
  __shared__ half8 As[64 * 4];
  __shared__ half8 Bs[64 * 4];
  const int bid = blockIdx.x;
  if (bid < 336)        trw_x_dev(cw1, Weff1, D0, KTOT1, bid, tile);
  else if (bid < 364)   vgemm_dev(aW1, cw1, Weff1, D0, KTOT1, bid - 336, As, Bs);
  else if (bid < 476)   trw_x_dev(cw2, Weff2, H, KTOT2, bid - 364, tile);
  else                  vgemm_dev(aW2, cw2, Weff2, H, KTOT2, bid - 476, As, Bs);
}

// ---------- att + store attA/attT fp16 ----------
template<int D>
__global__ __launch_bounds__(256) void k_attst(const f16* __restrict__ X1,
                                               const f16* __restrict__ X2,
                                               f16* __restrict__ attA,
                                               f16* __restrict__ attT) {
  __shared__ half8 As[64 * 4];
  __shared__ half8 Bs[64 * 4];
  __shared__ float n1s[64], n2s[64];
  __shared__ half8 atA[64 * 8];
  __shared__ half8 atT[64 * 8];

  const int b = blockIdx.x, tid = threadIdx.x;
  const int lane = tid & 63, wave = tid >> 6;
  const int wr = wave >> 1, wc = wave & 1;
  const int l15 = lane & 15, g = lane >> 4;
  const f16* __restrict__ x1 = X1 + (size_t)b * S * D;
  const f16* __restrict__ x2 = X2 + (size_t)b * S * D;

  floatx4 acc[2][2];
#pragma unroll
  for (int i = 0; i < 2; ++i)
#pragma unroll
    for (int j = 0; j < 2; ++j) acc[i][j] = (floatx4)0.f;
  float na1 = 0.f, na2 = 0.f;

  for (int k0 = 0; k0 < D; k0 += 32) {
    __syncthreads();
    {
      const int r = tid >> 2, c = tid & 3;
      const int p = r * 4 + (c ^ ((r >> 1) & 3));
      As[p] = *reinterpret_cast<const half8*>(x1 + (size_t)r * D + k0 + c * 8);
      Bs[p] = *reinterpret_cast<const half8*>(x2 + (size_t)r * D + k0 + c * 8);
    }
    __syncthreads();
    half8 af[2], bf[2];
#pragma unroll
    for (int fi = 0; fi < 2; ++fi) {
      const int row = wr * 32 + fi * 16 + l15;
      af[fi] = As[row * 4 + (g ^ ((row >> 1) & 3))];
    }
#pragma unroll
    for (int fj = 0; fj < 2; ++fj) {
      const int row = wc * 32 + fj * 16 + l15;
      bf[fj] = Bs[row * 4 + (g ^ ((row >> 1) & 3))];
    }
#pragma unroll
    for (int fi = 0; fi < 2; ++fi)
#pragma unroll
      for (int fj = 0; fj < 2; ++fj)
        acc[fi][fj] = __builtin_amdgcn_mfma_f32_16x16x32_f16(af[fi], bf[fj], acc[fi][fj], 0, 0, 0);
    if (tid < 64) {
      const int r = tid;
#pragma unroll
      for (int c = 0; c < 4; ++c) {
        half8 v = As[r * 4 + (c ^ ((r >> 1) & 3))];
#pragma unroll
        for (int e = 0; e < 8; ++e) { float f = (float)v[e]; na1 = fmaf(f, f, na1); }
      }
    } else if (tid >= 128 && tid < 192) {
      const int r = tid - 128;
#pragma unroll
      for (int c = 0; c < 4; ++c) {
        half8 v = Bs[r * 4 + (c ^ ((r >> 1) & 3))];
#pragma unroll
        for (int e = 0; e < 8; ++e) { float f = (float)v[e]; na2 = fmaf(f, f, na2); }
      }
    }
  }
  if (tid < 64) n1s[tid] = na1;
  if (tid >= 128 && tid < 192) n2s[tid - 128] = na2;
  __syncthreads();

  f16* atAe = reinterpret_cast<f16*>(atA);
  f16* atTe = reinterpret_cast<f16*>(atT);
#pragma unroll
  for (int fi = 0; fi < 2; ++fi)
#pragma unroll
    for (int fj = 0; fj < 2; ++fj)
#pragma unroll
      for (int r = 0; r < 4; ++r) {
        const int i = wr * 32 + fi * 16 + g * 4 + r;
        const int j = wc * 32 + fj * 16 + l15;
        float sq = fmaxf(n1s[i] + n2s[j] - 2.f * acc[fi][fj][r], 0.f);
        const f16 v = (f16)(1.f / (1.f + sqrtf(sq + EPSF)));
        atAe[(i * 8 + ((j >> 3) ^ (i & 7))) * 8 + (j & 7)] = v;
        atTe[(j * 8 + ((i >> 3) ^ (j & 7))) * 8 + (i & 7)] = v;
      }
  __syncthreads();
  half8* Ag = reinterpret_cast<half8*>(attA) + (size_t)b * 512;
  half8* Tg = reinterpret_cast<half8*>(attT) + (size_t)b * 512;
  for (int idx = tid; idx < 512; idx += 256) {
    const int i = idx >> 3, ch = idx & 7;
    Ag[idx] = atA[i * 8 + (ch ^ (i & 7))];
    Tg[idx] = atT[i * 8 + (ch ^ (i & 7))];
  }
}

// ---------- conv: T3/T4 counted-vmcnt pipeline, dbuf A-window, 3-buf B ----------
template<int DPC>
__global__ __launch_bounds__(256) void k_conv(const f16* __restrict__ X0,
                                              const f16* __restrict__ X1v,
                                              const f16* __restrict__ At0,
                                              const f16* __restrict__ At1,
                                              const f16* __restrict__ Weff,
                                              const float* __restrict__ bias,
                                              f16* __restrict__ O16_0,
                                              f16* __restrict__ O16_1) {
  constexpr int NDQX = DPC / 64;
  constexpr int NX7 = NDQX * 7;
  constexpr int NSTEP = NX7 + 7;
  constexpr int KTOT = NSTEP * 64;
  __shared__ half8 Wl[2][70 * 8];      // A-window, double-buffered (parity of window idx)
  __shared__ half8 B8[3][128 * 8];     // B tiles, triple-buffered (2-deep prefetch)

  const int tid = threadIdx.x;
  const int bid = blockIdx.x;
  const int xcd = bid & 7, slot = bid >> 3;
  const int n0 = (xcd >> 2) * 128;
  const int w = slot * 4 + (xcd & 3);
  const int z = w & 1, mblk = w >> 1;
  const int m0 = mblk * 64;
  const f16* __restrict__ Xs  = z ? X1v : X0;
  const f16* __restrict__ Ats = z ? At1 : At0;
  f16* __restrict__ Out16 = z ? O16_1 : O16_0;

  const int lane = tid & 63, wave = tid >> 6;
  const int wr = wave >> 1, wc = wave & 1;
  const int l15 = lane & 15, g = lane >> 4;
  const int r0 = tid >> 3, c8 = tid & 7;

  int jr[3] = {r0, r0 + 32, 64 + r0};
  int aoffX[3], aoffA[3];
  bool aval[3];
#pragma unroll
  for (int p = 0; p < 3; ++p) {
    const int u = m0 - 6 + jr[p];
    const int uc = u < 0 ? 0 : u;
    const int bn = uc / T70;
    const int tl = uc - bn * T70;
    aval[p] = (u >= 0) && (tl < S);
    aoffX[p] = (bn * S + tl) * DPC + c8 * 8;
    aoffA[p] = (bn * 64 + tl) * 64 + c8 * 8;
  }
  const bool has2 = (r0 < 6);
  const int bchunk0 = wave * 64 + lane;
  const f16* __restrict__ bsrc = Weff + (size_t)n0 * KTOT;

  floatx4 acc[2][4];
#pragma unroll
  for (int i = 0; i < 2; ++i)
#pragma unroll
    for (int j = 0; j < 4; ++j) acc[i][j] = (floatx4)0.f;

  half8 rA[3];
  auto aLoad = [&](const f16* __restrict__ src, const int* aoff, int co) {
#pragma unroll
    for (int p = 0; p < 2; ++p)
      rA[p] = aval[p] ? *reinterpret_cast<const half8*>(src + aoff[p] + co)
                      : (half8)(f16)0.f;
    if (has2)
      rA[2] = aval[2] ? *reinterpret_cast<const half8*>(src + aoff[2] + co)
                      : (half8)(f16)0.f;
  };
  auto aWrite = [&](int bufA) {
#pragma unroll
    for (int p = 0; p < 2; ++p) {
      const int j = jr[p];
      Wl[bufA][j * 8 + (c8 ^ (j & 7))] = rA[p];
    }
    if (has2) {
      const int j = jr[2];
      Wl[bufA][j * 8 + (c8 ^ (j & 7))] = rA[2];
    }
  };
  auto bStage = [&](int buf, int ks) {
    const int o = ks * 64;   // Weff columns are step-ordered
#pragma unroll
    for (int q = 0; q < 4; ++q) {
      const int chunk = q * 256 + bchunk0;
      const int r = chunk >> 3, cc = chunk & 7;
      gload16(bsrc + (size_t)r * KTOT + o + cc * 8, &B8[buf][q * 256 + wave * 64]);
    }
  };
  auto compute = [&](int ks) {
    const int k = ks % 7;
    const int buf = ks % 3;
    const int bufA = (ks / 7) & 1;
    half8 af[2][2], bf[4][2];
#pragma unroll
    for (int i = 0; i < 2; ++i) {
      const int j = wr * 32 + i * 16 + l15 + k;
#pragma unroll
      for (int s = 0; s < 2; ++s)
        af[i][s] = Wl[bufA][j * 8 + ((s * 4 + g) ^ (j & 7))];
    }
#pragma unroll
    for (int jx = 0; jx < 4; ++jx) {
      const int row = wc * 64 + jx * 16 + l15;
#pragma unroll
      for (int s = 0; s < 2; ++s)
        bf[jx][s] = B8[buf][row * 8 + ((s * 4 + g) ^ (row & 7))];
    }
    __builtin_amdgcn_s_setprio(1);
#pragma unroll
    for (int s = 0; s < 2; ++s)
#pragma unroll
      for (int i = 0; i < 2; ++i)
#pragma unroll
        for (int jx = 0; jx < 4; ++jx)
          acc[i][jx] = __builtin_amdgcn_mfma_f32_16x16x32_f16(af[i][s], bf[jx][s], acc[i][jx], 0, 0, 0);
    __builtin_amdgcn_s_setprio(0);
  };

  // prologue: B steps 0,1 in flight; A window 0 staged
  bStage(0, 0);
  aLoad(Xs, aoffX, 0);
  bStage(1, 1);
  aWrite(0);
  asm volatile("s_waitcnt vmcnt(4) lgkmcnt(0)" ::: "memory");  // B step0 + A writes done
  __builtin_amdgcn_s_barrier();
  __builtin_amdgcn_sched_barrier(0);

  for (int ks = 0; ks < NSTEP; ++ks) {
    const int nxt = ks + 1, nn = ks + 2;
    if (nn < NSTEP) bStage(nn % 3, nn);        // 2-deep prefetch
    if ((ks % 7) == 5) {                       // A-window prefetch into regs
      const int wnd = ks / 7 + 1;
      if (wnd < NDQX) aLoad(Xs, aoffX, wnd * 64);
      else if (wnd == NDQX) aLoad(Ats, aoffA, 0);
    }
    compute(ks);
    const bool awr = (nxt < NSTEP) && ((nxt % 7) == 0);
    if (awr) aWrite((nxt / 7) & 1);            // write OTHER A buffer — no pre-barrier needed
    if (nxt < NSTEP) {
      if (nn < NSTEP) {
        if (awr) asm volatile("s_waitcnt vmcnt(4) lgkmcnt(0)" ::: "memory");
        else     asm volatile("s_waitcnt vmcnt(4)" ::: "memory");
      } else {
        asm volatile("s_waitcnt vmcnt(0) lgkmcnt(0)" ::: "memory");
      }
      __builtin_amdgcn_s_barrier();
      __builtin_amdgcn_sched_barrier(0);
    }
  }

  // epilogue: fused bias + tanh, fp16 store
#pragma unroll
  for (int i = 0; i < 2; ++i) {
    const int mr = m0 + wr * 32 + i * 16 + g * 4;
#pragma unroll
    for (int jx = 0; jx < 4; ++jx) {
      const int h = n0 + wc * 64 + jx * 16 + l15;
      const float bv = bias[h];
#pragma unroll
      for (int r = 0; r < 4; ++r)
        Out16[(size_t)(mr + r) * H + h] = (f16)tanhf(acc[i][jx][r] + bv);
    }
  }
}

// ---------- fused att2-sums + all-pool mean + window pool (per batch) ----------
__global__ __launch_bounds__(256) void k_pool(const f16* __restrict__ lcTh,
                                              const f16* __restrict__ rcTh,
                                              float* __restrict__ LO1,
                                              float* __restrict__ RO1,
                                              f16* __restrict__ LI1h,
                                              f16* __restrict__ RI1h) {
  constexpr int W = T70, WP = 96, D = H;
  constexpr int FR = WP / 32;
  __shared__ half8 As[WP * 4];
  __shared__ half8 Bs[WP * 4];
  __shared__ float n1s[WP], n2s[WP];
  __shared__ float att_s[WP * (WP + 1)];   // phase2 reuses this as f16 wv[70][256]
  __shared__ float la_s[W], ra_s[W];

  const int b = blockIdx.x, tid = threadIdx.x;
  const int lane = tid & 63, wave = tid >> 6;
  const int wr = wave >> 1, wc = wave & 1;
  const int l15 = lane & 15, g = lane >> 4;
  const f16* __restrict__ x1 = lcTh + (size_t)b * W * D;
  const f16* __restrict__ x2 = rcTh + (size_t)b * W * D;

  // ---- phase 1: att2 + row/col sums ----
  floatx4 acc[FR][FR];
#pragma unroll
  for (int i = 0; i < FR; ++i)
#pragma unroll
    for (int j = 0; j < FR; ++j) acc[i][j] = (floatx4)0.f;
  float na1 = 0.f, na2 = 0.f;

  for (int k0 = 0; k0 < D; k0 += 32) {
    __syncthreads();
    for (int u = tid; u < WP * 4; u += 256) {
      const int r = u >> 2, c = u & 3;
      half8 v1 = (half8)(f16)0.f, v2 = (half8)(f16)0.f;
      if (r < W) {
        v1 = *reinterpret_cast<const half8*>(x1 + (size_t)r * D + k0 + c * 8);
        v2 = *reinterpret_cast<const half8*>(x2 + (size_t)r * D + k0 + c * 8);
      }
      const int p = r * 4 + (c ^ ((r >> 1) & 3));
      As[p] = v1;
      Bs[p] = v2;
    }
    __syncthreads();
    half8 af[FR], bf[FR];
#pragma unroll
    for (int fi = 0; fi < FR; ++fi) {
      const int row = wr * 16 * FR + fi * 16 + l15;
      af[fi] = As[row * 4 + (g ^ ((row >> 1) & 3))];
    }
#pragma unroll
    for (int fj = 0; fj < FR; ++fj) {
      const int row = wc * 16 * FR + fj * 16 + l15;
      bf[fj] = Bs[row * 4 + (g ^ ((row >> 1) & 3))];
    }
#pragma unroll
    for (int fi = 0; fi < FR; ++fi)
#pragma unroll
      for (int fj = 0; fj < FR; ++fj)
        acc[fi][fj] = __builtin_amdgcn_mfma_f32_16x16x32_f16(af[fi], bf[fj], acc[fi][fj], 0, 0, 0);
    if (tid < WP) {
      const int r = tid;
#pragma unroll
      for (int c = 0; c < 4; ++c) {
        half8 v = As[r * 4 + (c ^ ((r >> 1) & 3))];
#pragma unroll
        for (int e = 0; e < 8; ++e) { float f = (float)v[e]; na1 = fmaf(f, f, na1); }
      }
    } else if (tid >= 128 && tid < 128 + WP) {
      const int r = tid - 128;
#pragma unroll
      for (int c = 0; c < 4; ++c) {
        half8 v = Bs[r * 4 + (c ^ ((r >> 1) & 3))];
#pragma unroll
        for (int e = 0; e < 8; ++e) { float f = (float)v[e]; na2 = fmaf(f, f, na2); }
      }
    }
  }
  if (tid < WP) n1s[tid] = na1;
  if (tid >= 128 && tid < 128 + WP) n2s[tid - 128] = na2;
  __syncthreads();

#pragma unroll
  for (int fi = 0; fi < FR; ++fi)
#pragma unroll
    for (int fj = 0; fj < FR; ++fj)
#pragma unroll
      for (int r = 0; r < 4; ++r) {
        const int i = wr * 16 * FR + fi * 16 + g * 4 + r;
        const int j = wc * 16 * FR + fj * 16 + l15;
        if (i < W && j < W) {
          float sq = fmaxf(n1s[i] + n2s[j] - 2.f * acc[fi][fj][r], 0.f);
          att_s[i * (WP + 1) + j] = 1.f / (1.f + sqrtf(sq + EPSF));
        }
      }
  __syncthreads();
  if (tid < W) {
    float sum = 0.f;
    for (int j = 0; j < W; ++j) sum += att_s[tid * (WP + 1) + j];
    la_s[tid] = sum;
  }
  if (tid >= 128 && tid < 128 + W) {
    const int j = tid - 128;
    float sum = 0.f;
    for (int i = 0; i < W; ++i) sum += att_s[i * (WP + 1) + j];
    ra_s[j] = sum;
  }
  __syncthreads();

  // ---- phase 2: per-side mean + window pool (wv aliases att_s) ----
  f16 (*wv)[H] = reinterpret_cast<f16(*)[H]>(att_s);
  const int h = tid;
#pragma unroll
  for (int side = 0; side < 2; ++side) {
    const f16* __restrict__ xc = (side ? rcTh : lcTh) + (size_t)b * T70 * H;
    const float* __restrict__ av = side ? ra_s : la_s;
    float* __restrict__ LO = side ? RO1 : LO1;
    f16* __restrict__ LI = (side ? RI1h : LI1h) + (size_t)b * S * H;
    __syncthreads();   // protect wv from previous phase's readers
    float sum = 0.f;
    for (int t = 0; t < T70; ++t) {
      const float v = (float)xc[(size_t)t * H + h];
      sum += v;
      wv[t][h] = (f16)(v * av[t]);
    }
    LO[(size_t)b * H + h] = sum * (1.f / T70);
    __syncthreads();
    for (int s = 0; s < S; ++s) {
      float a = 0.f;
#pragma unroll
      for (int j = 0; j < KW; ++j) a += (float)wv[s + j][h];
      LI[(size_t)s * H + h] = (f16)a;
    }
  }
}

// ---------- cosine sims + LO2/RO2 means (fused) + final tiny GEMM ----------
__global__ __launch_bounds__(256) void k_final(const float* __restrict__ LO0,
                                               const float* __restrict__ RO0,
                                               const float* __restrict__ LO1,
                                               const float* __restrict__ RO1,
                                               const f16* __restrict__ lcTh,
                                               const f16* __restrict__ rcTh,
                                               const float* __restrict__ out_w,
                                               const float* __restrict__ out_b,
                                               float* __restrict__ out) {
  const int b = blockIdx.x;
  const int tid = threadIdx.x;
  __shared__ float red[3][4];
  __shared__ float sims[3];

  // fused LO2/RO2: thread tid owns channel h = tid (H == 256)
  float lo2 = 0.f, ro2 = 0.f;
  {
    const f16* lp = lcTh + (size_t)b * T70 * H + tid;
    const f16* rp = rcTh + (size_t)b * T70 * H + tid;
    for (int t = 0; t < T70; ++t) {
      lo2 += (float)lp[(size_t)t * H];
      ro2 += (float)rp[(size_t)t * H];
    }
    lo2 *= (1.f / T70);
    ro2 *= (1.f / T70);
  }

  const float* Ls[2] = {LO0 + (size_t)b * D0, LO1 + (size_t)b * H};
  const float* Rs[2] = {RO0 + (size_t)b * D0, RO1 + (size_t)b * H};
  const int dims[2] = {D0, H};
#pragma unroll
  for (int p = 0; p < 3; ++p) {
    float dot, q1, q2;
    if (p < 2) {
      dot = 0.f; q1 = 0.f; q2 = 0.f;
      for (int i = tid; i < dims[p]; i += 256) {
        const float v1 = Ls[p][i], v2 = Rs[p][i];
        dot = fmaf(v1, v2, dot);
        q1  = fmaf(v1, v1, q1);
        q2  = fmaf(v2, v2, q2);
      }
    } else {
      dot = lo2 * ro2; q1 = lo2 * lo2; q2 = ro2 * ro2;
    }
#pragma unroll
    for (int off = 32; off > 0; off >>= 1) {
      dot += __shfl_down(dot, off);
      q1  += __shfl_down(q1, off);
      q2  += __shfl_down(q2, off);
    }
    if ((tid & 63) == 0) { red[0][tid >> 6] = dot; red[1][tid >> 6] = q1; red[2][tid >> 6] = q2; }
    __syncthreads();
    if (tid == 0) {
      float d = red[0][0] + red[0][1] + red[0][2] + red[0][3];
      float a = red[1][0] + red[1][1] + red[1][2] + red[1][3];
      float c = red[2][0] + red[2][1] + red[2][2] + red[2][3];
      sims[p] = d / (sqrtf(a) * sqrtf(c) + EPSF);
    }
    __syncthreads();
  }
  if (tid < NC) {
    float v = out_b[tid];
#pragma unroll
    for (int k = 0; k < 3; ++k) v = fmaf(sims[k], out_w[k * NC + tid], v);
    out[b * NC + tid] = v;
  }
}

extern "C" void kernel_launch(void* const* d_in, const int* in_sizes, int n_in,
                              void* d_out, int out_size, void* d_ws, size_t ws_size,
                              hipStream_t stream) {
  const float* premise    = (const float*)d_in[0];
  const float* hypothesis = (const float*)d_in[1];
  const float* aW1        = (const float*)d_in[2];
  const float* conv1_w    = (const float*)d_in[3];
  const float* conv1_b    = (const float*)d_in[4];
  const float* aW2        = (const float*)d_in[5];
  const float* conv2_w    = (const float*)d_in[6];
  const float* conv2_b    = (const float*)d_in[7];
  const float* out_w      = (const float*)d_in[8];
  const float* out_b      = (const float*)d_in[9];
  float* out = (float*)d_out;

  char* ws = (char*)d_ws;
  size_t off = 0;
  auto alloc = [&](size_t bytes) {
    void* p = ws + off;
    off += (bytes + 255) & ~(size_t)255;
    return p;
  };
  f16*   Weff1 = (f16*)alloc((size_t)H * KTOT1 * 2);
  f16*   Weff2 = (f16*)alloc((size_t)H * KTOT2 * 2);
  f16*   Xh    = (f16*)alloc((size_t)B * S * D0 * 2);
  f16*   Yh    = (f16*)alloc((size_t)B * S * D0 * 2);
  f16*   attA  = (f16*)alloc((size_t)B * S * S * 2);   // reused layer1+2
  f16*   attT  = (f16*)alloc((size_t)B * S * S * 2);
  f16*   LI1h  = (f16*)alloc((size_t)B * S * H * 2);
  f16*   RI1h  = (f16*)alloc((size_t)B * S * H * 2);
  f16*   lcTh  = (f16*)alloc((size_t)B * T70 * H * 2); // reused layer2
  f16*   rcTh  = (f16*)alloc((size_t)B * T70 * H * 2);
  float* LO0   = (float*)alloc((size_t)B * D0 * 4);
  float* RO0   = (float*)alloc((size_t)B * D0 * 4);
  float* LO1   = (float*)alloc((size_t)B * H * 4);
  float* RO1   = (float*)alloc((size_t)B * H * 4);

  // 0. fused converts+means; fused weight prep (one launch)
  k_cvtmean<<<dim3(B * (D0 / 4) / 256, 2), 256, 0, stream>>>(premise, hypothesis, Xh, Yh, LO0, RO0);
  k_wprep<<<504, 256, 0, stream>>>(conv1_w, aW1, Weff1, conv2_w, aW2, Weff2);
  // 1. att1 -> attA/attT
  k_attst<D0><<<B, 256, 0, stream>>>(Xh, Yh, attA, attT);
  // 2. conv1 (counted-vmcnt pipeline) -> lcTh/rcTh fp16
  k_conv<D0><<<560, 256, 0, stream>>>(Xh, Yh, attA, attT, Weff1, conv1_b, lcTh, rcTh);
  // 3. fused att2-sums + mean + wpool
  k_pool<<<B, 256, 0, stream>>>(lcTh, rcTh, LO1, RO1, LI1h, RI1h);
  // 4. layer-2 att -> attA/attT
  k_attst<H><<<B, 256, 0, stream>>>(LI1h, RI1h, attA, attT);
  // 5. conv2 -> reuse lcTh/rcTh
  k_conv<H><<<560, 256, 0, stream>>>(LI1h, RI1h, attA, attT, Weff2, conv2_b, lcTh, rcTh);
  // 6. final (fused LO2/RO2 means)
  k_final<<<B, 256, 0, stream>>>(LO0, RO0, LO1, RO1, lcTh, rcTh, out_w, out_b, out);
}

// Round 10
// 212.776 us; speedup vs baseline: 1.4092x; 1.4092x over previous
//
#include <hip/hip_runtime.h>
#include <math.h>

typedef _Float16 f16;
typedef _Float16 half8 __attribute__((ext_vector_type(8)));
typedef _Float16 half4 __attribute__((ext_vector_type(4)));
typedef float floatx4 __attribute__((ext_vector_type(4)));

constexpr int B   = 128;
constexpr int S   = 64;
constexpr int D0  = 768;
constexpr int H   = 256;
constexpr int KW  = 7;
constexpr int NC  = 3;
constexpr int T70 = S + KW - 1;  // 70
constexpr float EPSF = 1e-12f;
constexpr int KTOT1 = ((D0 / 64) * 7 + 7) * 64;   // 5824
constexpr int KTOT2 = ((H  / 64) * 7 + 7) * 64;   // 2240

// global_load_lds width=16: linear LDS dest (wave-uniform base + lane*16), per-lane global src
__device__ __forceinline__ void gload16(const void* g, void* l) {
  __builtin_amdgcn_global_load_lds(
      (const __attribute__((address_space(1))) unsigned int*)g,
      (__attribute__((address_space(3))) unsigned int*)l, 16, 0, 0);
}

// ---------- fused fp32->fp16 convert + mean over t, both sides ----------
__global__ __launch_bounds__(256) void k_cvtmean(const float* __restrict__ in0,
                                                 const float* __restrict__ in1,
                                                 f16* __restrict__ oh0,
                                                 f16* __restrict__ oh1,
                                                 float* __restrict__ mn0,
                                                 float* __restrict__ mn1) {
  constexpr int D4 = D0 / 4;
  const int side = blockIdx.y;
  const float* __restrict__ in = side ? in1 : in0;
  f16* __restrict__ outh = side ? oh1 : oh0;
  float* __restrict__ mean = side ? mn1 : mn0;
  const int idx = blockIdx.x * 256 + threadIdx.x;   // grid.x = B*D4/256 = 96
  const int b = idx / D4, f4 = idx % D4;
  const float4* __restrict__ src = reinterpret_cast<const float4*>(in) + (size_t)b * S * D4 + f4;
  half4* __restrict__ dst = reinterpret_cast<half4*>(outh) + (size_t)b * S * D4 + f4;
  float4 acc = {0.f, 0.f, 0.f, 0.f};
  for (int t = 0; t < S; ++t) {
    float4 v = src[(size_t)t * D4];
    acc.x += v.x; acc.y += v.y; acc.z += v.z; acc.w += v.w;
    half4 o = {(f16)v.x, (f16)v.y, (f16)v.z, (f16)v.w};
    dst[(size_t)t * D4] = o;
  }
  const float inv = 1.f / S;
  mean[(size_t)b * D0 + f4 * 4 + 0] = acc.x * inv;
  mean[(size_t)b * D0 + f4 * 4 + 1] = acc.y * inv;
  mean[(size_t)b * D0 + f4 * 4 + 2] = acc.z * inv;
  mean[(size_t)b * D0 + f4 * 4 + 3] = acc.w * inv;
}

// ---------- fused weight prep: X-part transpose + V-GEMM, both layers, one launch ----------
// Weff layout (pre-swizzled): X cols (dq*7+k)*64, att cols (NX7+k)*64;
// within each 64-col group, 16B chunk e>>3 stored at (e>>3)^(h&7).
__device__ __forceinline__ void trw_x_dev(const float* __restrict__ cw,
                                          f16* __restrict__ Weff,
                                          int DPC, int Ktot, int t,
                                          f16 (*tile)[65]) {
  const int nb = DPC / 64;
  const int k = t / (nb * 4);
  const int rem = t % (nb * 4);
  const int h0 = (rem / nb) * 64, dd0 = (rem % nb) * 64;
  const int tx = threadIdx.x & 63, ty = threadIdx.x >> 6;
#pragma unroll
  for (int i = 0; i < 64; i += 4) {
    int dd = dd0 + i + ty;
    tile[i + ty][tx] = (f16)cw[(size_t)((dd * KW + k) * 2 + 0) * H + h0 + tx];
  }
  __syncthreads();
  const int sbase = ((dd0 >> 6) * 7 + k) * 64;
#pragma unroll
  for (int i = 0; i < 64; i += 4) {
    int h = h0 + i + ty;
    int col = sbase + (((tx >> 3) ^ (h & 7)) << 3) + (tx & 7);
    Weff[(size_t)h * Ktot + col] = tile[tx][i + ty];
  }
}

__device__ __forceinline__ void vgemm_dev(const float* __restrict__ aW,
                                          const float* __restrict__ cw,
                                          f16* __restrict__ Weff,
                                          int D, int Ktot, int t,
                                          half8* As, half8* Bs) {
  const int kk = t % 7;
  const int h0 = (t / 7) * 64;
  const int tid = threadIdx.x;
  const int lane = tid & 63, wave = tid >> 6;
  const int wr = wave >> 1, wc = wave & 1;
  const int l15 = lane & 15, g = lane >> 4;

  floatx4 acc[2][2];
#pragma unroll
  for (int i = 0; i < 2; ++i)
#pragma unroll
    for (int j = 0; j < 2; ++j) acc[i][j] = (floatx4)0.f;

  for (int k0 = 0; k0 < D; k0 += 32) {
    __syncthreads();
    {
      const int r = tid >> 2, cch = tid & 3;
      const float4* s = reinterpret_cast<const float4*>(aW + (size_t)r * D + k0 + cch * 8);
      float4 v0 = s[0], v1 = s[1];
      half8 hv = {(f16)v0.x, (f16)v0.y, (f16)v0.z, (f16)v0.w,
                  (f16)v1.x, (f16)v1.y, (f16)v1.z, (f16)v1.w};
      As[r * 4 + (cch ^ ((r >> 1) & 3))] = hv;
      const int hrow = tid & 63, kc = tid >> 6;
      half8 bv;
#pragma unroll
      for (int e = 0; e < 8; ++e) {
        const int d = k0 + kc * 8 + e;
        bv[e] = (f16)cw[(size_t)((d * KW + kk) * 2 + 1) * H + h0 + hrow];
      }
      Bs[hrow * 4 + (kc ^ ((hrow >> 1) & 3))] = bv;
    }
    __syncthreads();
    half8 af[2], bf[2];
#pragma unroll
    for (int fi = 0; fi < 2; ++fi) {
      const int row = wr * 32 + fi * 16 + l15;
      af[fi] = As[row * 4 + (g ^ ((row >> 1) & 3))];
    }
#pragma unroll
    for (int fj = 0; fj < 2; ++fj) {
      const int row = wc * 32 + fj * 16 + l15;
      bf[fj] = Bs[row * 4 + (g ^ ((row >> 1) & 3))];
    }
#pragma unroll
    for (int fi = 0; fi < 2; ++fi)
#pragma unroll
      for (int fj = 0; fj < 2; ++fj)
        acc[fi][fj] = __builtin_amdgcn_mfma_f32_16x16x32_f16(af[fi], bf[fj], acc[fi][fj], 0, 0, 0);
  }
  const int base = ((D / 64) * 7 + kk) * 64;
#pragma unroll
  for (int fi = 0; fi < 2; ++fi)
#pragma unroll
    for (int fj = 0; fj < 2; ++fj)
#pragma unroll
      for (int r = 0; r < 4; ++r) {
        const int j = wr * 32 + fi * 16 + g * 4 + r;
        const int h = h0 + wc * 32 + fj * 16 + l15;
        const int col = base + (((j >> 3) ^ (h & 7)) << 3) + (j & 7);
        Weff[(size_t)h * Ktot + col] = (f16)acc[fi][fj][r];
      }
}

__global__ __launch_bounds__(256) void k_wprep(const float* __restrict__ cw1,
                                               const float* __restrict__ aW1,
                                               f16* __restrict__ Weff1,
                                               const float* __restrict__ cw2,
                                               const float* __restrict__ aW2,
                                               f16* __restrict__ Weff2) {
  __shared__ f16 tile[64][65];
  __shared__ half8 As[64 * 4];
  __shared__ half8 Bs[64 * 4];
  const int bid = blockIdx.x;
  if (bid < 336)        trw_x_dev(cw1, Weff1, D0, KTOT1, bid, tile);
  else if (bid < 364)   vgemm_dev(aW1, cw1, Weff1, D0, KTOT1, bid - 336, As, Bs);
  else if (bid < 476)   trw_x_dev(cw2, Weff2, H, KTOT2, bid - 364, tile);
  else                  vgemm_dev(aW2, cw2, Weff2, H, KTOT2, bid - 476, As, Bs);
}

// ---------- att + store attA/attT fp16 ----------
template<int D>
__global__ __launch_bounds__(256) void k_attst(const f16* __restrict__ X1,
                                               const f16* __restrict__ X2,
                                               f16* __restrict__ attA,
                                               f16* __restrict__ attT) {
  __shared__ half8 As[64 * 4];
  __shared__ half8 Bs[64 * 4];
  __shared__ float n1s[64], n2s[64];
  __shared__ half8 atA[64 * 8];
  __shared__ half8 atT[64 * 8];

  const int b = blockIdx.x, tid = threadIdx.x;
  const int lane = tid & 63, wave = tid >> 6;
  const int wr = wave >> 1, wc = wave & 1;
  const int l15 = lane & 15, g = lane >> 4;
  const f16* __restrict__ x1 = X1 + (size_t)b * S * D;
  const f16* __restrict__ x2 = X2 + (size_t)b * S * D;

  floatx4 acc[2][2];
#pragma unroll
  for (int i = 0; i < 2; ++i)
#pragma unroll
    for (int j = 0; j < 2; ++j) acc[i][j] = (floatx4)0.f;
  float na1 = 0.f, na2 = 0.f;

  for (int k0 = 0; k0 < D; k0 += 32) {
    __syncthreads();
    {
      const int r = tid >> 2, c = tid & 3;
      const int p = r * 4 + (c ^ ((r >> 1) & 3));
      As[p] = *reinterpret_cast<const half8*>(x1 + (size_t)r * D + k0 + c * 8);
      Bs[p] = *reinterpret_cast<const half8*>(x2 + (size_t)r * D + k0 + c * 8);
    }
    __syncthreads();
    half8 af[2], bf[2];
#pragma unroll
    for (int fi = 0; fi < 2; ++fi) {
      const int row = wr * 32 + fi * 16 + l15;
      af[fi] = As[row * 4 + (g ^ ((row >> 1) & 3))];
    }
#pragma unroll
    for (int fj = 0; fj < 2; ++fj) {
      const int row = wc * 32 + fj * 16 + l15;
      bf[fj] = Bs[row * 4 + (g ^ ((row >> 1) & 3))];
    }
#pragma unroll
    for (int fi = 0; fi < 2; ++fi)
#pragma unroll
      for (int fj = 0; fj < 2; ++fj)
        acc[fi][fj] = __builtin_amdgcn_mfma_f32_16x16x32_f16(af[fi], bf[fj], acc[fi][fj], 0, 0, 0);
    if (tid < 64) {
      const int r = tid;
#pragma unroll
      for (int c = 0; c < 4; ++c) {
        half8 v = As[r * 4 + (c ^ ((r >> 1) & 3))];
#pragma unroll
        for (int e = 0; e < 8; ++e) { float f = (float)v[e]; na1 = fmaf(f, f, na1); }
      }
    } else if (tid >= 128 && tid < 192) {
      const int r = tid - 128;
#pragma unroll
      for (int c = 0; c < 4; ++c) {
        half8 v = Bs[r * 4 + (c ^ ((r >> 1) & 3))];
#pragma unroll
        for (int e = 0; e < 8; ++e) { float f = (float)v[e]; na2 = fmaf(f, f, na2); }
      }
    }
  }
  if (tid < 64) n1s[tid] = na1;
  if (tid >= 128 && tid < 192) n2s[tid - 128] = na2;
  __syncthreads();

  f16* atAe = reinterpret_cast<f16*>(atA);
  f16* atTe = reinterpret_cast<f16*>(atT);
#pragma unroll
  for (int fi = 0; fi < 2; ++fi)
#pragma unroll
    for (int fj = 0; fj < 2; ++fj)
#pragma unroll
      for (int r = 0; r < 4; ++r) {
        const int i = wr * 32 + fi * 16 + g * 4 + r;
        const int j = wc * 32 + fj * 16 + l15;
        float sq = fmaxf(n1s[i] + n2s[j] - 2.f * acc[fi][fj][r], 0.f);
        const f16 v = (f16)(1.f / (1.f + sqrtf(sq + EPSF)));
        atAe[(i * 8 + ((j >> 3) ^ (i & 7))) * 8 + (j & 7)] = v;
        atTe[(j * 8 + ((i >> 3) ^ (j & 7))) * 8 + (i & 7)] = v;
      }
  __syncthreads();
  half8* Ag = reinterpret_cast<half8*>(attA) + (size_t)b * 512;
  half8* Tg = reinterpret_cast<half8*>(attT) + (size_t)b * 512;
  for (int idx = tid; idx < 512; idx += 256) {
    const int i = idx >> 3, ch = idx & 7;
    Ag[idx] = atA[i * 8 + (ch ^ (i & 7))];
    Tg[idx] = atT[i * 8 + (ch ^ (i & 7))];
  }
}

// ---------- conv (R8 proven structure): 4 waves 32x64, A-window + gload_lds B ----------
// K-steps: ks < NX7: X-phase (dq = ks/7, tap k = ks%7); ks >= NX7: att-phase (tap = ks-NX7).
template<int DPC>
__global__ __launch_bounds__(256) void k_conv(const f16* __restrict__ X0,
                                              const f16* __restrict__ X1v,
                                              const f16* __restrict__ At0,
                                              const f16* __restrict__ At1,
                                              const f16* __restrict__ Weff,
                                              const float* __restrict__ bias,
                                              f16* __restrict__ O16_0,
                                              f16* __restrict__ O16_1) {
  constexpr int NDQX = DPC / 64;
  constexpr int NX7 = NDQX * 7;
  constexpr int NSTEP = NX7 + 7;
  constexpr int KTOT = NSTEP * 64;
  __shared__ half8 Wl[70 * 8];         // A-window (one phase at a time)
  __shared__ half8 B8[2][128 * 8];     // B tiles, double-buffered, linear

  const int tid = threadIdx.x;
  const int bid = blockIdx.x;
  const int xcd = bid & 7, slot = bid >> 3;
  const int n0 = (xcd >> 2) * 128;
  const int w = slot * 4 + (xcd & 3);
  const int z = w & 1, mblk = w >> 1;
  const int m0 = mblk * 64;
  const f16* __restrict__ Xs  = z ? X1v : X0;
  const f16* __restrict__ Ats = z ? At1 : At0;
  f16* __restrict__ Out16 = z ? O16_1 : O16_0;

  const int lane = tid & 63, wave = tid >> 6;
  const int wr = wave >> 1, wc = wave & 1;
  const int l15 = lane & 15, g = lane >> 4;
  const int r0 = tid >> 3, c8 = tid & 7;

  int jr[3] = {r0, r0 + 32, 64 + r0};
  int aoffX[3], aoffA[3];
  bool aval[3];
#pragma unroll
  for (int p = 0; p < 3; ++p) {
    const int u = m0 - 6 + jr[p];
    const int uc = u < 0 ? 0 : u;
    const int bn = uc / T70;
    const int tl = uc - bn * T70;
    aval[p] = (u >= 0) && (tl < S);
    aoffX[p] = (bn * S + tl) * DPC + c8 * 8;
    aoffA[p] = (bn * 64 + tl) * 64 + c8 * 8;
  }
  const bool has2 = (r0 < 6);
  const int bchunk0 = wave * 64 + lane;
  const f16* __restrict__ bsrc = Weff + (size_t)n0 * KTOT;

  floatx4 acc[2][4];
#pragma unroll
  for (int i = 0; i < 2; ++i)
#pragma unroll
    for (int j = 0; j < 4; ++j) acc[i][j] = (floatx4)0.f;

  half8 rA[3];
  auto aLoad = [&](const f16* __restrict__ src, const int* aoff, int co) {
#pragma unroll
    for (int p = 0; p < 2; ++p)
      rA[p] = aval[p] ? *reinterpret_cast<const half8*>(src + aoff[p] + co)
                      : (half8)(f16)0.f;
    if (has2)
      rA[2] = aval[2] ? *reinterpret_cast<const half8*>(src + aoff[2] + co)
                      : (half8)(f16)0.f;
  };
  auto aWrite = [&]() {
#pragma unroll
    for (int p = 0; p < 2; ++p) {
      const int j = jr[p];
      Wl[j * 8 + (c8 ^ (j & 7))] = rA[p];
    }
    if (has2) {
      const int j = jr[2];
      Wl[j * 8 + (c8 ^ (j & 7))] = rA[2];
    }
  };
  auto bStage = [&](int buf, int ks) {
    const int o = ks * 64;   // Weff columns are step-ordered
#pragma unroll
    for (int q = 0; q < 4; ++q) {
      const int chunk = q * 256 + bchunk0;
      const int r = chunk >> 3, cc = chunk & 7;
      gload16(bsrc + (size_t)r * KTOT + o + cc * 8, &B8[buf][q * 256 + wave * 64]);
    }
  };
  auto compute = [&](int ks) {
    const int k = (ks < NX7) ? (ks % 7) : (ks - NX7);
    const int buf = ks & 1;
    half8 af[2][2], bf[4][2];
#pragma unroll
    for (int i = 0; i < 2; ++i) {
      const int j = wr * 32 + i * 16 + l15 + k;
#pragma unroll
      for (int s = 0; s < 2; ++s)
        af[i][s] = Wl[j * 8 + ((s * 4 + g) ^ (j & 7))];
    }
#pragma unroll
    for (int jx = 0; jx < 4; ++jx) {
      const int row = wc * 64 + jx * 16 + l15;
#pragma unroll
      for (int s = 0; s < 2; ++s)
        bf[jx][s] = B8[buf][row * 8 + ((s * 4 + g) ^ (row & 7))];
    }
#pragma unroll
    for (int s = 0; s < 2; ++s)
#pragma unroll
      for (int i = 0; i < 2; ++i)
#pragma unroll
        for (int jx = 0; jx < 4; ++jx)
          acc[i][jx] = __builtin_amdgcn_mfma_f32_16x16x32_f16(af[i][s], bf[jx][s], acc[i][jx], 0, 0, 0);
  };

  // prologue: B(step0) direct-to-LDS, A-window dq0 reg->LDS
  bStage(0, 0);
  aLoad(Xs, aoffX, 0);
  aWrite();
  __syncthreads();

  for (int ks = 0; ks < NSTEP; ++ks) {
    const int nxt = ks + 1;
    const bool more = nxt < NSTEP;
    if (more) {
      bStage(nxt & 1, nxt);                  // async, lands by end-of-step barrier
      if (ks % 7 == 5) {                     // prefetch next A-window into regs
        const int wnd = ks / 7 + 1;
        if (wnd < NDQX) aLoad(Xs, aoffX, wnd * 64);
        else if (wnd == NDQX) aLoad(Ats, aoffA, 0);
      }
    }
    compute(ks);
    if (more && (nxt % 7 == 0)) { __syncthreads(); aWrite(); }
    __syncthreads();
  }

  // epilogue: fused bias + tanh, fp16 store
#pragma unroll
  for (int i = 0; i < 2; ++i) {
    const int mr = m0 + wr * 32 + i * 16 + g * 4;
#pragma unroll
    for (int jx = 0; jx < 4; ++jx) {
      const int h = n0 + wc * 64 + jx * 16 + l15;
      const float bv = bias[h];
#pragma unroll
      for (int r = 0; r < 4; ++r)
        Out16[(size_t)(mr + r) * H + h] = (f16)tanhf(acc[i][jx][r] + bv);
    }
  }
}

// ---------- fused att2-sums + all-pool mean + window pool (per batch) ----------
__global__ __launch_bounds__(256) void k_pool(const f16* __restrict__ lcTh,
                                              const f16* __restrict__ rcTh,
                                              float* __restrict__ LO1,
                                              float* __restrict__ RO1,
                                              f16* __restrict__ LI1h,
                                              f16* __restrict__ RI1h) {
  constexpr int W = T70, WP = 96, D = H;
  constexpr int FR = WP / 32;
  __shared__ half8 As[WP * 4];
  __shared__ half8 Bs[WP * 4];
  __shared__ float n1s[WP], n2s[WP];
  __shared__ float att_s[WP * (WP + 1)];   // phase2 reuses this as f16 wv[70][256]
  __shared__ float la_s[W], ra_s[W];

  const int b = blockIdx.x, tid = threadIdx.x;
  const int lane = tid & 63, wave = tid >> 6;
  const int wr = wave >> 1, wc = wave & 1;
  const int l15 = lane & 15, g = lane >> 4;
  const f16* __restrict__ x1 = lcTh + (size_t)b * W * D;
  const f16* __restrict__ x2 = rcTh + (size_t)b * W * D;

  // ---- phase 1: att2 + row/col sums ----
  floatx4 acc[FR][FR];
#pragma unroll
  for (int i = 0; i < FR; ++i)
#pragma unroll
    for (int j = 0; j < FR; ++j) acc[i][j] = (floatx4)0.f;
  float na1 = 0.f, na2 = 0.f;

  for (int k0 = 0; k0 < D; k0 += 32) {
    __syncthreads();
    for (int u = tid; u < WP * 4; u += 256) {
      const int r = u >> 2, c = u & 3;
      half8 v1 = (half8)(f16)0.f, v2 = (half8)(f16)0.f;
      if (r < W) {
        v1 = *reinterpret_cast<const half8*>(x1 + (size_t)r * D + k0 + c * 8);
        v2 = *reinterpret_cast<const half8*>(x2 + (size_t)r * D + k0 + c * 8);
      }
      const int p = r * 4 + (c ^ ((r >> 1) & 3));
      As[p] = v1;
      Bs[p] = v2;
    }
    __syncthreads();
    half8 af[FR], bf[FR];
#pragma unroll
    for (int fi = 0; fi < FR; ++fi) {
      const int row = wr * 16 * FR + fi * 16 + l15;
      af[fi] = As[row * 4 + (g ^ ((row >> 1) & 3))];
    }
#pragma unroll
    for (int fj = 0; fj < FR; ++fj) {
      const int row = wc * 16 * FR + fj * 16 + l15;
      bf[fj] = Bs[row * 4 + (g ^ ((row >> 1) & 3))];
    }
#pragma unroll
    for (int fi = 0; fi < FR; ++fi)
#pragma unroll
      for (int fj = 0; fj < FR; ++fj)
        acc[fi][fj] = __builtin_amdgcn_mfma_f32_16x16x32_f16(af[fi], bf[fj], acc[fi][fj], 0, 0, 0);
    if (tid < WP) {
      const int r = tid;
#pragma unroll
      for (int c = 0; c < 4; ++c) {
        half8 v = As[r * 4 + (c ^ ((r >> 1) & 3))];
#pragma unroll
        for (int e = 0; e < 8; ++e) { float f = (float)v[e]; na1 = fmaf(f, f, na1); }
      }
    } else if (tid >= 128 && tid < 128 + WP) {
      const int r = tid - 128;
#pragma unroll
      for (int c = 0; c < 4; ++c) {
        half8 v = Bs[r * 4 + (c ^ ((r >> 1) & 3))];
#pragma unroll
        for (int e = 0; e < 8; ++e) { float f = (float)v[e]; na2 = fmaf(f, f, na2); }
      }
    }
  }
  if (tid < WP) n1s[tid] = na1;
  if (tid >= 128 && tid < 128 + WP) n2s[tid - 128] = na2;
  __syncthreads();

#pragma unroll
  for (int fi = 0; fi < FR; ++fi)
#pragma unroll
    for (int fj = 0; fj < FR; ++fj)
#pragma unroll
      for (int r = 0; r < 4; ++r) {
        const int i = wr * 16 * FR + fi * 16 + g * 4 + r;
        const int j = wc * 16 * FR + fj * 16 + l15;
        if (i < W && j < W) {
          float sq = fmaxf(n1s[i] + n2s[j] - 2.f * acc[fi][fj][r], 0.f);
          att_s[i * (WP + 1) + j] = 1.f / (1.f + sqrtf(sq + EPSF));
        }
      }
  __syncthreads();
  if (tid < W) {
    float sum = 0.f;
    for (int j = 0; j < W; ++j) sum += att_s[tid * (WP + 1) + j];
    la_s[tid] = sum;
  }
  if (tid >= 128 && tid < 128 + W) {
    const int j = tid - 128;
    float sum = 0.f;
    for (int i = 0; i < W; ++i) sum += att_s[i * (WP + 1) + j];
    ra_s[j] = sum;
  }
  __syncthreads();

  // ---- phase 2: per-side mean + window pool (wv aliases att_s) ----
  f16 (*wv)[H] = reinterpret_cast<f16(*)[H]>(att_s);
  const int h = tid;
#pragma unroll
  for (int side = 0; side < 2; ++side) {
    const f16* __restrict__ xc = (side ? rcTh : lcTh) + (size_t)b * T70 * H;
    const float* __restrict__ av = side ? ra_s : la_s;
    float* __restrict__ LO = side ? RO1 : LO1;
    f16* __restrict__ LI = (side ? RI1h : LI1h) + (size_t)b * S * H;
    __syncthreads();   // protect wv from previous phase's readers
    float sum = 0.f;
    for (int t = 0; t < T70; ++t) {
      const float v = (float)xc[(size_t)t * H + h];
      sum += v;
      wv[t][h] = (f16)(v * av[t]);
    }
    LO[(size_t)b * H + h] = sum * (1.f / T70);
    __syncthreads();
    for (int s = 0; s < S; ++s) {
      float a = 0.f;
#pragma unroll
      for (int j = 0; j < KW; ++j) a += (float)wv[s + j][h];
      LI[(size_t)s * H + h] = (f16)a;
    }
  }
}

// ---------- cosine sims + LO2/RO2 means (fused) + final tiny GEMM ----------
__global__ __launch_bounds__(256) void k_final(const float* __restrict__ LO0,
                                               const float* __restrict__ RO0,
                                               const float* __restrict__ LO1,
                                               const float* __restrict__ RO1,
                                               const f16* __restrict__ lcTh,
                                               const f16* __restrict__ rcTh,
                                               const float* __restrict__ out_w,
                                               const float* __restrict__ out_b,
                                               float* __restrict__ out) {
  const int b = blockIdx.x;
  const int tid = threadIdx.x;
  __shared__ float red[3][4];
  __shared__ float sims[3];

  // fused LO2/RO2: thread tid owns channel h = tid (H == 256)
  float lo2 = 0.f, ro2 = 0.f;
  {
    const f16* lp = lcTh + (size_t)b * T70 * H + tid;
    const f16* rp = rcTh + (size_t)b * T70 * H + tid;
    for (int t = 0; t < T70; ++t) {
      lo2 += (float)lp[(size_t)t * H];
      ro2 += (float)rp[(size_t)t * H];
    }
    lo2 *= (1.f / T70);
    ro2 *= (1.f / T70);
  }

  const float* Ls[2] = {LO0 + (size_t)b * D0, LO1 + (size_t)b * H};
  const float* Rs[2] = {RO0 + (size_t)b * D0, RO1 + (size_t)b * H};
  const int dims[2] = {D0, H};
#pragma unroll
  for (int p = 0; p < 3; ++p) {
    float dot, q1, q2;
    if (p < 2) {
      dot = 0.f; q1 = 0.f; q2 = 0.f;
      for (int i = tid; i < dims[p]; i += 256) {
        const float v1 = Ls[p][i], v2 = Rs[p][i];
        dot = fmaf(v1, v2, dot);
        q1  = fmaf(v1, v1, q1);
        q2  = fmaf(v2, v2, q2);
      }
    } else {
      dot = lo2 * ro2; q1 = lo2 * lo2; q2 = ro2 * ro2;
    }
#pragma unroll
    for (int off = 32; off > 0; off >>= 1) {
      dot += __shfl_down(dot, off);
      q1  += __shfl_down(q1, off);
      q2  += __shfl_down(q2, off);
    }
    if ((tid & 63) == 0) { red[0][tid >> 6] = dot; red[1][tid >> 6] = q1; red[2][tid >> 6] = q2; }
    __syncthreads();
    if (tid == 0) {
      float d = red[0][0] + red[0][1] + red[0][2] + red[0][3];
      float a = red[1][0] + red[1][1] + red[1][2] + red[1][3];
      float c = red[2][0] + red[2][1] + red[2][2] + red[2][3];
      sims[p] = d / (sqrtf(a) * sqrtf(c) + EPSF);
    }
    __syncthreads();
  }
  if (tid < NC) {
    float v = out_b[tid];
#pragma unroll
    for (int k = 0; k < 3; ++k) v = fmaf(sims[k], out_w[k * NC + tid], v);
    out[b * NC + tid] = v;
  }
}

extern "C" void kernel_launch(void* const* d_in, const int* in_sizes, int n_in,
                              void* d_out, int out_size, void* d_ws, size_t ws_size,
                              hipStream_t stream) {
  const float* premise    = (const float*)d_in[0];
  const float* hypothesis = (const float*)d_in[1];
  const float* aW1        = (const float*)d_in[2];
  const float* conv1_w    = (const float*)d_in[3];
  const float* conv1_b    = (const float*)d_in[4];
  const float* aW2        = (const float*)d_in[5];
  const float* conv2_w    = (const float*)d_in[6];
  const float* conv2_b    = (const float*)d_in[7];
  const float* out_w      = (const float*)d_in[8];
  const float* out_b      = (const float*)d_in[9];
  float* out = (float*)d_out;

  char* ws = (char*)d_ws;
  size_t off = 0;
  auto alloc = [&](size_t bytes) {
    void* p = ws + off;
    off += (bytes + 255) & ~(size_t)255;
    return p;
  };
  f16*   Weff1 = (f16*)alloc((size_t)H * KTOT1 * 2);
  f16*   Weff2 = (f16*)alloc((size_t)H * KTOT2 * 2);
  f16*   Xh    = (f16*)alloc((size_t)B * S * D0 * 2);
  f16*   Yh    = (f16*)alloc((size_t)B * S * D0 * 2);
  f16*   attA  = (f16*)alloc((size_t)B * S * S * 2);   // reused layer1+2
  f16*   attT  = (f16*)alloc((size_t)B * S * S * 2);
  f16*   LI1h  = (f16*)alloc((size_t)B * S * H * 2);
  f16*   RI1h  = (f16*)alloc((size_t)B * S * H * 2);
  f16*   lcTh  = (f16*)alloc((size_t)B * T70 * H * 2); // reused layer2
  f16*   rcTh  = (f16*)alloc((size_t)B * T70 * H * 2);
  float* LO0   = (float*)alloc((size_t)B * D0 * 4);
  float* RO0   = (float*)alloc((size_t)B * D0 * 4);
  float* LO1   = (float*)alloc((size_t)B * H * 4);
  float* RO1   = (float*)alloc((size_t)B * H * 4);

  // 0. fused converts+means; fused weight prep (one launch)
  k_cvtmean<<<dim3(B * (D0 / 4) / 256, 2), 256, 0, stream>>>(premise, hypothesis, Xh, Yh, LO0, RO0);
  k_wprep<<<504, 256, 0, stream>>>(conv1_w, aW1, Weff1, conv2_w, aW2, Weff2);
  // 1. att1 -> attA/attT
  k_attst<D0><<<B, 256, 0, stream>>>(Xh, Yh, attA, attT);
  // 2. conv1 (R8 proven structure) -> lcTh/rcTh fp16
  k_conv<D0><<<560, 256, 0, stream>>>(Xh, Yh, attA, attT, Weff1, conv1_b, lcTh, rcTh);
  // 3. fused att2-sums + mean + wpool
  k_pool<<<B, 256, 0, stream>>>(lcTh, rcTh, LO1, RO1, LI1h, RI1h);
  // 4. layer-2 att -> attA/attT
  k_attst<H><<<B, 256, 0, stream>>>(LI1h, RI1h, attA, attT);
  // 5. conv2 -> reuse lcTh/rcTh
  k_conv<H><<<560, 256, 0, stream>>>(LI1h, RI1h, attA, attT, Weff2, conv2_b, lcTh, rcTh);
  // 6. final (fused LO2/RO2 means)
  k_final<<<B, 256, 0, stream>>>(LO0, RO0, LO1, RO1, lcTh, rcTh, out_w, out_b, out);
}